// Round 12
// baseline (343.111 us; speedup 1.0000x reference)
//
#include <hip/hip_runtime.h>
#include <cstddef>
#include <cstdint>

// Problem: B=2, S=2048, E=1024, H=16, D=64.  Softmax over HEADS (ref quirk).
#define BATCH 2
#define S_LEN 2048
#define E_DIM 1024
#define NH    16
#define HD    64
#define M_ROWS (BATCH * S_LEN)   // 4096

// fold softmax scale into Q at projection time: 1/sqrt(64) * log2(e)
#define QSCALE 0.18033688011112042f

typedef unsigned short u16;
typedef short     bf16x8 __attribute__((ext_vector_type(8)));
typedef _Float16  f16x8  __attribute__((ext_vector_type(8)));
typedef __fp16    h16x2  __attribute__((ext_vector_type(2)));   // cvt_pkrtz return type
typedef float     f32x4  __attribute__((ext_vector_type(4)));

__device__ __forceinline__ u16 f2bf(float f) {
    union { float f; unsigned u; } v; v.f = f;
    unsigned r = v.u + 0x7fffu + ((v.u >> 16) & 1u);   // RNE
    return (u16)(r >> 16);
}
__device__ __forceinline__ float bf2f(u16 h) {
    union { unsigned u; float f; } v; v.u = ((unsigned)h) << 16;
    return v.f;
}
__device__ __forceinline__ u16 f2h(float f) {
    union { __fp16 h; u16 u; } cv; cv.h = (__fp16)f; return cv.u;
}

// async global->LDS DMA, 16 B per lane (global_load_lds_dwordx4).
__device__ __forceinline__ void load_lds16(const u16* g, u16* l) {
    __builtin_amdgcn_global_load_lds(
        (const __attribute__((address_space(1))) unsigned int*)g,
        (__attribute__((address_space(3))) unsigned int*)l, 16, 0, 0);
}

// ---------------------------------------------------------------------------
// fp32 -> bf16 bulk convert (n % 4 == 0)
// ---------------------------------------------------------------------------
__global__ void cvt_bf16(const float* __restrict__ in, u16* __restrict__ out, int n)
{
    int i = (blockIdx.x * 256 + threadIdx.x) * 4;
    if (i + 3 < n) {
        float4 v = *(const float4*)(in + i);
        u16 o[4] = { f2bf(v.x), f2bf(v.y), f2bf(v.z), f2bf(v.w) };
        *(uint2*)(out + i) = *(const uint2*)o;
    }
}

// three QKV weight matrices -> concat bf16 buffer, one launch (grid.y = seg)
__global__ void cvt_w3(const float* __restrict__ Wq, const float* __restrict__ Wk,
                       const float* __restrict__ Wv, u16* __restrict__ out)
{
    const int seg = blockIdx.y;
    const float* src = (seg == 0) ? Wq : (seg == 1) ? Wk : Wv;
    int i = (blockIdx.x * 256 + threadIdx.x) * 4;
    float4 v = *(const float4*)(src + i);
    u16 o[4] = { f2bf(v.x), f2bf(v.y), f2bf(v.z), f2bf(v.w) };
    *(uint2*)(out + (size_t)seg * E_DIM * E_DIM + i) = *(const uint2*)o;
}

// ---------------------------------------------------------------------------
// ctx = a + b  (bf16 in, fp32 add, bf16 out)
// ---------------------------------------------------------------------------
__global__ void combine_ctx(const u16* __restrict__ a, const u16* __restrict__ b,
                            u16* __restrict__ c, int n)
{
    int i = (blockIdx.x * 256 + threadIdx.x) * 4;
    if (i + 3 < n) {
        uint2 ua = *(const uint2*)(a + i);
        uint2 ub = *(const uint2*)(b + i);
        const u16* pa = (const u16*)&ua; const u16* pb = (const u16*)&ub;
        u16 o[4];
#pragma unroll
        for (int j = 0; j < 4; ++j) o[j] = f2bf(bf2f(pa[j]) + bf2f(pb[j]));
        *(uint2*)(c + i) = *(const uint2*)o;
    }
}

// ---------------------------------------------------------------------------
// Fused QKV projection GEMM (m97-style DMA staging).
//   seg 0 -> Q, bf16, PRE-SCALED by QSCALE (softmax scale folded in)
//   seg 1 -> K, bf16
//   seg 2 -> V, written TRANSPOSED Vt[b][e][s] in FP16 (PV runs fp16 MFMA)
// ---------------------------------------------------------------------------
__global__ __launch_bounds__(256)
void gemm_qkv(const u16* __restrict__ A, const u16* __restrict__ W3,
              const float* __restrict__ bq, const float* __restrict__ bk,
              const float* __restrict__ bv,
              u16* __restrict__ Qb, u16* __restrict__ Kb, u16* __restrict__ Vtb)
{
    __shared__ u16 Al[128 * 32];
    __shared__ u16 Bl[128 * 32];
    const int K = E_DIM;
    const int t = threadIdx.x;
    const int w = t >> 6, lane = t & 63;
    const int quad = lane >> 4, lm = lane & 15;
    const int wy = w >> 1, wx = w & 1;
    const int m0 = blockIdx.x * 128, n0 = blockIdx.y * 128;
    const int lrow  = lane >> 2;
    const int lcol8 = (lane & 3) * 8;

    f32x4 acc[4][4] = {};

    for (int kb = 0; kb < K; kb += 32) {
        __syncthreads();
#pragma unroll
        for (int i = 0; i < 2; ++i) {
            const int r0 = w * 32 + i * 16;
            load_lds16(A  + (size_t)(m0 + r0 + lrow) * K + kb + lcol8, &Al[r0 * 32]);
            load_lds16(W3 + (size_t)(n0 + r0 + lrow) * K + kb + lcol8, &Bl[r0 * 32]);
        }
        __syncthreads();

        bf16x8 af[4], bfr[4];
#pragma unroll
        for (int i = 0; i < 4; ++i)
            af[i] = *(const bf16x8*)(Al + (wy * 64 + i * 16 + lm) * 32 + quad * 8);
#pragma unroll
        for (int j = 0; j < 4; ++j)
            bfr[j] = *(const bf16x8*)(Bl + (wx * 64 + j * 16 + lm) * 32 + quad * 8);
#pragma unroll
        for (int i = 0; i < 4; ++i)
#pragma unroll
            for (int j = 0; j < 4; ++j)
                acc[i][j] = __builtin_amdgcn_mfma_f32_16x16x32_bf16(af[i], bfr[j], acc[i][j], 0, 0, 0);
    }

    const int seg = n0 >> 10;            // 0=Q, 1=K, 2=V
    const int nl0 = n0 & 1023;
    const float* bs = (seg == 0) ? bq : (seg == 1) ? bk : bv;

    if (seg < 2) {
        u16* dst = (seg == 0) ? Qb : Kb;
        const float scl = (seg == 0) ? QSCALE : 1.0f;
#pragma unroll
        for (int j = 0; j < 4; ++j) {
            const int n = nl0 + wx * 64 + j * 16 + lm;
            const float bias = bs[n];
#pragma unroll
            for (int i = 0; i < 4; ++i) {
                const int mrow = m0 + wy * 64 + i * 16 + quad * 4;
#pragma unroll
                for (int rg = 0; rg < 4; ++rg)
                    dst[(size_t)(mrow + rg) * E_DIM + n] = f2bf((acc[i][j][rg] + bias) * scl);
            }
        }
    } else {
        // V: fp16, transposed -> Vt[b][e][s]
#pragma unroll
        for (int j = 0; j < 4; ++j) {
            const int n = nl0 + wx * 64 + j * 16 + lm;
            const float bias = bs[n];
#pragma unroll
            for (int i = 0; i < 4; ++i) {
                const int mrow = m0 + wy * 64 + i * 16 + quad * 4;
                const int batch = mrow >> 11;
                const int sloc  = mrow & 2047;
                u16 o[4];
#pragma unroll
                for (int rg = 0; rg < 4; ++rg) {
                    union { _Float16 h; u16 u; } cv;
                    cv.h = (_Float16)(acc[i][j][rg] + bias);
                    o[rg] = cv.u;
                }
                *(uint2*)&Vtb[(size_t)batch * E_DIM * S_LEN + (size_t)n * S_LEN + sloc]
                    = *(const uint2*)o;
            }
        }
    }
}

// ---------------------------------------------------------------------------
// Output projection GEMM — unchanged.
// ---------------------------------------------------------------------------
__global__ __launch_bounds__(256)
void gemm_wo(const u16* __restrict__ A, const u16* __restrict__ B,
             const float* __restrict__ bias, float* __restrict__ C)
{
    __shared__ u16 Al[128 * 32];
    __shared__ u16 Bl[128 * 32];
    const int K = E_DIM, N = E_DIM;
    const int t = threadIdx.x;
    const int w = t >> 6, lane = t & 63;
    const int quad = lane >> 4, lm = lane & 15;
    const int wy = w >> 1, wx = w & 1;
    const int m0 = blockIdx.x * 128, n0 = blockIdx.y * 128;
    const int lrow  = lane >> 2;
    const int lcol8 = (lane & 3) * 8;

    f32x4 acc[4][4] = {};

    for (int kb = 0; kb < K; kb += 32) {
        __syncthreads();
#pragma unroll
        for (int i = 0; i < 2; ++i) {
            const int r0 = w * 32 + i * 16;
            load_lds16(A + (size_t)(m0 + r0 + lrow) * K + kb + lcol8, &Al[r0 * 32]);
            load_lds16(B + (size_t)(n0 + r0 + lrow) * K + kb + lcol8, &Bl[r0 * 32]);
        }
        __syncthreads();

        bf16x8 af[4], bfr[4];
#pragma unroll
        for (int i = 0; i < 4; ++i)
            af[i] = *(const bf16x8*)(Al + (wy * 64 + i * 16 + lm) * 32 + quad * 8);
#pragma unroll
        for (int j = 0; j < 4; ++j)
            bfr[j] = *(const bf16x8*)(Bl + (wx * 64 + j * 16 + lm) * 32 + quad * 8);
#pragma unroll
        for (int i = 0; i < 4; ++i)
#pragma unroll
            for (int j = 0; j < 4; ++j)
                acc[i][j] = __builtin_amdgcn_mfma_f32_16x16x32_bf16(af[i], bfr[j], acc[i][j], 0, 0, 0);
    }

#pragma unroll
    for (int j = 0; j < 4; ++j) {
        const int n = n0 + wx * 64 + j * 16 + lm;
        const float bs = bias[n];
#pragma unroll
        for (int i = 0; i < 4; ++i) {
            const int mrow = m0 + wy * 64 + i * 16 + quad * 4;
#pragma unroll
            for (int rg = 0; rg < 4; ++rg)
                C[(size_t)(mrow + rg) * N + n] = acc[i][j][rg] + bs;
        }
    }
}

// ---------------------------------------------------------------------------
// attn_v15: ONE HEAD PER WAVE -> acc 64->32 regs -> 4 waves/SIMD.
//   R8-R11 established: HW allocates arch+acc VGPRs from the unified file
//   with {64,128,256} quanta; oacc=64 forced the 256-quantum (2 waves/SIMD).
//   1024 thr / 16 waves, wave w owns head w, 32 q/block, 32-k chunks.
//   Per-thread: qf16 + oacc32 + vf16 + softmax16 + addr ~= 110 <= 128.
//   __launch_bounds__(1024,4) enforces the 128 cap (a 1024-thr block NEEDS
//   4 waves/SIMD to be resident at all).  Occupancy 2 -> 4 waves/SIMD.
//   Same per-block work/L2-traffic as v12/v13; softmax 1 slot/thread.
//   S4h rotate-by-quad (v13's free-write fix); P5 pitch 40 (16B-aligned
//   b128 PV reads).  KSPLIT=2, combo->XCD-pair pinning, grid 256 = 1
//   block/CU, single pass.
// ---------------------------------------------------------------------------
__global__ __launch_bounds__(1024, 4)
void attn_v15(const u16* __restrict__ Q, const u16* __restrict__ K,
              const u16* __restrict__ Vt, u16* __restrict__ ctxA,
              u16* __restrict__ ctxB)
{
    __shared__ __align__(16) u16 smem[38912];   // 77824 B
    u16* S4h = smem;                 // [1024 slots][18] fp16 halves = 36864 B
    u16* P5  = smem + 18432;         // [16h][32q][40] halves       = 40960 B

    const int t     = threadIdx.x;   // 0..1023
    const int w     = t >> 6;        // 0..15  == this wave's head
    const int lane  = t & 63;
    const int quad  = lane >> 4, lm = lane & 15;
    const int h     = w;

    // combo -> XCD-pair pinning (model: XCD = blockIdx % 8).
    const int i     = blockIdx.x;        // 0..255
    const int xcd   = i & 7;
    const int combo = xcd >> 1;          // 0..3
    const int b     = combo >> 1;
    const int khalf = combo & 1;
    const int slot  = i >> 3;            // 0..31
    const int qt    = ((xcd & 1) << 5) | slot;   // 0..63
    const int q0    = qt * 32;

    const size_t qbase = ((size_t)b * S_LEN + q0) * E_DIM;
    const size_t kmat  = (size_t)b * S_LEN * E_DIM;
    const size_t vtb   = (size_t)b * E_DIM * S_LEN;

    // Q fragments: [subtile][hf] for THIS head only (16 regs)
    bf16x8 qf[2][2];
#pragma unroll
    for (int s = 0; s < 2; ++s)
#pragma unroll
        for (int hf = 0; hf < 2; ++hf)
            qf[s][hf] = *(const bf16x8*)(Q + qbase
                        + (size_t)(s * 16 + lm) * E_DIM
                        + h * 64 + hf * 32 + quad * 8);

    f32x4 oacc[2][4] = {};   // [subtile][dtile] = 32 acc regs
    const int kbeg = khalf * (S_LEN / 2);
    const int sq = t & 31, sk = t >> 5;  // softmax: ONE slot (q=sq, k=sk)
    const int qrot = (sq + 8 * ((sk >> 2) & 3)) & 31;   // reader-side rotation

    for (int c = 0; c < (S_LEN / 2) / 32; ++c) {   // 32 chunks of 32 k
        const int k0 = kbeg + c * 32;

        // ---- swapped QK^T: this head, 2 kt x 2 subtiles ----
#pragma unroll
        for (int kt = 0; kt < 2; ++kt) {
            bf16x8 kf0 = *(const bf16x8*)(K + kmat
                         + (size_t)(k0 + kt * 16 + lm) * E_DIM
                         + h * 64 + quad * 8);
            bf16x8 kf1 = *(const bf16x8*)(K + kmat
                         + (size_t)(k0 + kt * 16 + lm) * E_DIM
                         + h * 64 + 32 + quad * 8);
            f32x4 sacc[2];
#pragma unroll
            for (int s = 0; s < 2; ++s) {
                f32x4 sf = {};
                sf = __builtin_amdgcn_mfma_f32_16x16x32_bf16(kf0, qf[s][0], sf, 0, 0, 0);
                sf = __builtin_amdgcn_mfma_f32_16x16x32_bf16(kf1, qf[s][1], sf, 0, 0, 0);
                sacc[s] = sf;
            }
            // scalar fp16 store per (s,rg); rotate-by-quad slot:
            // bank = 9*qph + (h>>1) with qph covering 0..31 2x -> free.
#pragma unroll
            for (int s = 0; s < 2; ++s)
#pragma unroll
                for (int rg = 0; rg < 4; ++rg) {
                    const int kl  = kt * 16 + quad * 4 + rg;          // 0..31
                    const int qph = ((s * 16 + lm) + 8 * quad) & 31;  // rotated
                    S4h[(size_t)(kl * 32 + qph) * 18 + h] = f2h(sacc[s][rg]);
                }
        }

        // ---- V prefetch: this head, 4 dt (16 regs); serves both subtiles ----
        f16x8 vf[4];
#pragma unroll
        for (int dt = 0; dt < 4; ++dt)
            vf[dt] = *(const f16x8*)(Vt + vtb
                     + (size_t)(h * 64 + dt * 16 + lm) * S_LEN
                     + k0 + quad * 8);

        asm volatile("s_waitcnt lgkmcnt(0)" ::: "memory");
        __builtin_amdgcn_s_barrier();   // B2: S4h visible everywhere

        // ---- register softmax over heads: exactly ONE (k,q) slot ----
        {
            const u16* base = S4h + (size_t)(sk * 32 + qrot) * 18;
            union { uint4 u; __fp16 hh[8]; } r0, r1;
            r0.u = *(const uint4*)(base);
            r1.u = *(const uint4*)(base + 8);
            float s[16];
#pragma unroll
            for (int z = 0; z < 8; ++z) {
                s[z]     = (float)r0.hh[z];
                s[8 + z] = (float)r1.hh[z];
            }
            const float m =
                fmaxf(fmaxf(fmaxf(fmaxf(s[0], s[1]), fmaxf(s[2], s[3])),
                            fmaxf(fmaxf(s[4], s[5]), fmaxf(s[6], s[7]))),
                      fmaxf(fmaxf(fmaxf(s[8], s[9]), fmaxf(s[10], s[11])),
                            fmaxf(fmaxf(s[12], s[13]), fmaxf(s[14], s[15]))));
#pragma unroll
            for (int hh = 0; hh < 16; ++hh)
                s[hh] = __builtin_amdgcn_exp2f(s[hh] - m);   // scale folded into Q
            const float sum =
                (((s[0] + s[1]) + (s[2] + s[3])) + ((s[4] + s[5]) + (s[6] + s[7]))) +
                (((s[8] + s[9]) + (s[10] + s[11])) + ((s[12] + s[13]) + (s[14] + s[15])));
            const float inv = __builtin_amdgcn_rcpf(sum);
#pragma unroll
            for (int hh = 0; hh < 16; ++hh)
                P5[(size_t)hh * 1280 + sq * 40 + sk] = f2h(s[hh] * inv);
        }

        asm volatile("s_waitcnt lgkmcnt(0)" ::: "memory");
        __builtin_amdgcn_s_barrier();   // B3: P5 visible; all S4h/P5 reads retired

        // ---- PV: this head, 2 subtiles x 4 dt ----
#pragma unroll
        for (int s = 0; s < 2; ++s) {
            f16x8 pa = *(const f16x8*)(P5 + (size_t)h * 1280
                                       + (s * 16 + lm) * 40 + quad * 8);
#pragma unroll
            for (int dt = 0; dt < 4; ++dt)
                oacc[s][dt] = __builtin_amdgcn_mfma_f32_16x16x32_f16(
                                  pa, vf[dt], oacc[s][dt], 0, 0, 0);
        }
    }

    __syncthreads();
    u16* Ol = smem;          // [32 q][1024 e] = 32768 u16 <= 38912 u16
#pragma unroll
    for (int s = 0; s < 2; ++s)
#pragma unroll
        for (int dt = 0; dt < 4; ++dt)
#pragma unroll
            for (int rg = 0; rg < 4; ++rg)
                Ol[(size_t)(s * 16 + quad * 4 + rg) * 1024 + h * 64 + dt * 16 + lm]
                    = f2bf(oacc[s][dt][rg]);
    __syncthreads();
    u16* dst = khalf ? ctxB : ctxA;
#pragma unroll
    for (int i2 = 0; i2 < 4; ++i2) {
        const int unit = i2 * 1024 + t;             // 4096 units total
        const int r = unit >> 7, cu = unit & 127;   // r 0..31
        *(bf16x8*)(dst + ((size_t)b * S_LEN + q0 + r) * E_DIM + cu * 8) =
            *(const bf16x8*)(Ol + (size_t)r * 1024 + cu * 8);
    }
}

// ---------------------------------------------------------------------------
extern "C" void kernel_launch(void* const* d_in, const int* in_sizes, int n_in,
                              void* d_out, int out_size, void* d_ws, size_t ws_size,
                              hipStream_t stream)
{
    const float* x  = (const float*)d_in[0];
    const float* Wq = (const float*)d_in[1];
    const float* bq = (const float*)d_in[2];
    const float* Wk = (const float*)d_in[3];
    const float* bk = (const float*)d_in[4];
    const float* Wv = (const float*)d_in[5];
    const float* bv = (const float*)d_in[6];
    const float* Wo = (const float*)d_in[7];
    const float* bo = (const float*)d_in[8];
    float* out = (float*)d_out;

    // bf16/fp16 workspace (u16 elems), 56 MB:
    const size_t MAT = (size_t)M_ROWS * E_DIM;   // 4M elems
    const size_t WSZ = (size_t)E_DIM * E_DIM;    // 1M elems
    u16* xb   = (u16*)d_ws;          // x; later combined ctx
    u16* W3   = xb   + MAT;          // Wq|Wk|Wv concat [3072][1024]
    u16* Wob  = W3   + 3 * WSZ;
    u16* Qb   = Wob  + WSZ;
    u16* Kb   = Qb   + MAT;
    u16* Vtb  = Kb   + MAT;          // V transposed [b][e][s], FP16
    u16* ctxA = Vtb  + MAT;
    u16* ctxB = ctxA + MAT;

    // 1) convert inputs to bf16 (QKV weights in one merged launch)
    cvt_bf16<<<(int)(MAT / 1024), 256, 0, stream>>>(x, xb, (int)MAT);
    dim3 wgrid(WSZ / 1024, 3);
    cvt_w3<<<wgrid, 256, 0, stream>>>(Wq, Wk, Wv, W3);
    cvt_bf16<<<(int)(WSZ / 1024), 256, 0, stream>>>(Wo, Wob, (int)WSZ);

    // 2) fused QKV projection (Q pre-scaled, V fp16-transposed)
    dim3 qkvgrid(M_ROWS / 128, 3 * E_DIM / 128);   // 32 x 24 = 768 blocks
    gemm_qkv<<<qkvgrid, 256, 0, stream>>>(xb, W3, bq, bk, bv, Qb, Kb, Vtb);

    // 3) fused MFMA attention: 1 head/wave, 1024 thr, 4 waves/SIMD,
    //    32 q/block, KSPLIT=2, XCD-pinned, grid 256 = 1 block/CU
    attn_v15<<<BATCH * 64 * 2, 1024, 0, stream>>>(Qb, Kb, Vtb, ctxA, ctxB);

    // 4) combine k-halves into xb (x is dead)
    combine_ctx<<<(int)(MAT / 1024), 256, 0, stream>>>(ctxA, ctxB, xb, (int)MAT);

    // 5) output projection (fp32 out)
    dim3 ogrid(M_ROWS / 128, E_DIM / 128);         // 32 x 8
    gemm_wo<<<ogrid, 256, 0, stream>>>(xb, Wob, bo, out);
}

// Round 13
// 298.036 us; speedup vs baseline: 1.1512x; 1.1512x over previous
//
#include <hip/hip_runtime.h>
#include <cstddef>
#include <cstdint>

// Problem: B=2, S=2048, E=1024, H=16, D=64.  Softmax over HEADS (ref quirk).
#define BATCH 2
#define S_LEN 2048
#define E_DIM 1024
#define NH    16
#define HD    64
#define M_ROWS (BATCH * S_LEN)   // 4096

// fold softmax scale into Q at projection time: 1/sqrt(64) * log2(e)
#define QSCALE 0.18033688011112042f

typedef unsigned short u16;
typedef short     bf16x8 __attribute__((ext_vector_type(8)));
typedef _Float16  f16x8  __attribute__((ext_vector_type(8)));
typedef __fp16    h16x2  __attribute__((ext_vector_type(2)));   // cvt_pkrtz return type
typedef float     f32x4  __attribute__((ext_vector_type(4)));

__device__ __forceinline__ u16 f2bf(float f) {
    union { float f; unsigned u; } v; v.f = f;
    unsigned r = v.u + 0x7fffu + ((v.u >> 16) & 1u);   // RNE
    return (u16)(r >> 16);
}
__device__ __forceinline__ float bf2f(u16 h) {
    union { unsigned u; float f; } v; v.u = ((unsigned)h) << 16;
    return v.f;
}

// async global->LDS DMA, 16 B per lane (global_load_lds_dwordx4).
__device__ __forceinline__ void load_lds16(const u16* g, u16* l) {
    __builtin_amdgcn_global_load_lds(
        (const __attribute__((address_space(1))) unsigned int*)g,
        (__attribute__((address_space(3))) unsigned int*)l, 16, 0, 0);
}

// ---------------------------------------------------------------------------
// fp32 -> bf16 bulk convert (n % 4 == 0)
// ---------------------------------------------------------------------------
__global__ void cvt_bf16(const float* __restrict__ in, u16* __restrict__ out, int n)
{
    int i = (blockIdx.x * 256 + threadIdx.x) * 4;
    if (i + 3 < n) {
        float4 v = *(const float4*)(in + i);
        u16 o[4] = { f2bf(v.x), f2bf(v.y), f2bf(v.z), f2bf(v.w) };
        *(uint2*)(out + i) = *(const uint2*)o;
    }
}

// three QKV weight matrices -> concat bf16 buffer, one launch (grid.y = seg)
__global__ void cvt_w3(const float* __restrict__ Wq, const float* __restrict__ Wk,
                       const float* __restrict__ Wv, u16* __restrict__ out)
{
    const int seg = blockIdx.y;
    const float* src = (seg == 0) ? Wq : (seg == 1) ? Wk : Wv;
    int i = (blockIdx.x * 256 + threadIdx.x) * 4;
    float4 v = *(const float4*)(src + i);
    u16 o[4] = { f2bf(v.x), f2bf(v.y), f2bf(v.z), f2bf(v.w) };
    *(uint2*)(out + (size_t)seg * E_DIM * E_DIM + i) = *(const uint2*)o;
}

// ---------------------------------------------------------------------------
// ctx = a + b  (bf16 in, fp32 add, bf16 out)
// ---------------------------------------------------------------------------
__global__ void combine_ctx(const u16* __restrict__ a, const u16* __restrict__ b,
                            u16* __restrict__ c, int n)
{
    int i = (blockIdx.x * 256 + threadIdx.x) * 4;
    if (i + 3 < n) {
        uint2 ua = *(const uint2*)(a + i);
        uint2 ub = *(const uint2*)(b + i);
        const u16* pa = (const u16*)&ua; const u16* pb = (const u16*)&ub;
        u16 o[4];
#pragma unroll
        for (int j = 0; j < 4; ++j) o[j] = f2bf(bf2f(pa[j]) + bf2f(pb[j]));
        *(uint2*)(c + i) = *(const uint2*)o;
    }
}

// ---------------------------------------------------------------------------
// Fused QKV projection GEMM (m97-style DMA staging).
//   seg 0 -> Q, bf16, PRE-SCALED by QSCALE (softmax scale folded in)
//   seg 1 -> K, bf16
//   seg 2 -> V, written TRANSPOSED Vt[b][e][s] in FP16 (PV runs fp16 MFMA)
// ---------------------------------------------------------------------------
__global__ __launch_bounds__(256)
void gemm_qkv(const u16* __restrict__ A, const u16* __restrict__ W3,
              const float* __restrict__ bq, const float* __restrict__ bk,
              const float* __restrict__ bv,
              u16* __restrict__ Qb, u16* __restrict__ Kb, u16* __restrict__ Vtb)
{
    __shared__ u16 Al[128 * 32];
    __shared__ u16 Bl[128 * 32];
    const int K = E_DIM;
    const int t = threadIdx.x;
    const int w = t >> 6, lane = t & 63;
    const int quad = lane >> 4, lm = lane & 15;
    const int wy = w >> 1, wx = w & 1;
    const int m0 = blockIdx.x * 128, n0 = blockIdx.y * 128;
    const int lrow  = lane >> 2;
    const int lcol8 = (lane & 3) * 8;

    f32x4 acc[4][4] = {};

    for (int kb = 0; kb < K; kb += 32) {
        __syncthreads();
#pragma unroll
        for (int i = 0; i < 2; ++i) {
            const int r0 = w * 32 + i * 16;
            load_lds16(A  + (size_t)(m0 + r0 + lrow) * K + kb + lcol8, &Al[r0 * 32]);
            load_lds16(W3 + (size_t)(n0 + r0 + lrow) * K + kb + lcol8, &Bl[r0 * 32]);
        }
        __syncthreads();

        bf16x8 af[4], bfr[4];
#pragma unroll
        for (int i = 0; i < 4; ++i)
            af[i] = *(const bf16x8*)(Al + (wy * 64 + i * 16 + lm) * 32 + quad * 8);
#pragma unroll
        for (int j = 0; j < 4; ++j)
            bfr[j] = *(const bf16x8*)(Bl + (wx * 64 + j * 16 + lm) * 32 + quad * 8);
#pragma unroll
        for (int i = 0; i < 4; ++i)
#pragma unroll
            for (int j = 0; j < 4; ++j)
                acc[i][j] = __builtin_amdgcn_mfma_f32_16x16x32_bf16(af[i], bfr[j], acc[i][j], 0, 0, 0);
    }

    const int seg = n0 >> 10;            // 0=Q, 1=K, 2=V
    const int nl0 = n0 & 1023;
    const float* bs = (seg == 0) ? bq : (seg == 1) ? bk : bv;

    if (seg < 2) {
        u16* dst = (seg == 0) ? Qb : Kb;
        const float scl = (seg == 0) ? QSCALE : 1.0f;
#pragma unroll
        for (int j = 0; j < 4; ++j) {
            const int n = nl0 + wx * 64 + j * 16 + lm;
            const float bias = bs[n];
#pragma unroll
            for (int i = 0; i < 4; ++i) {
                const int mrow = m0 + wy * 64 + i * 16 + quad * 4;
#pragma unroll
                for (int rg = 0; rg < 4; ++rg)
                    dst[(size_t)(mrow + rg) * E_DIM + n] = f2bf((acc[i][j][rg] + bias) * scl);
            }
        }
    } else {
        // V: fp16, transposed -> Vt[b][e][s]
#pragma unroll
        for (int j = 0; j < 4; ++j) {
            const int n = nl0 + wx * 64 + j * 16 + lm;
            const float bias = bs[n];
#pragma unroll
            for (int i = 0; i < 4; ++i) {
                const int mrow = m0 + wy * 64 + i * 16 + quad * 4;
                const int batch = mrow >> 11;
                const int sloc  = mrow & 2047;
                u16 o[4];
#pragma unroll
                for (int rg = 0; rg < 4; ++rg) {
                    union { _Float16 h; u16 u; } cv;
                    cv.h = (_Float16)(acc[i][j][rg] + bias);
                    o[rg] = cv.u;
                }
                *(uint2*)&Vtb[(size_t)batch * E_DIM * S_LEN + (size_t)n * S_LEN + sloc]
                    = *(const uint2*)o;
            }
        }
    }
}

// ---------------------------------------------------------------------------
// Output projection GEMM — unchanged.
// ---------------------------------------------------------------------------
__global__ __launch_bounds__(256)
void gemm_wo(const u16* __restrict__ A, const u16* __restrict__ B,
             const float* __restrict__ bias, float* __restrict__ C)
{
    __shared__ u16 Al[128 * 32];
    __shared__ u16 Bl[128 * 32];
    const int K = E_DIM, N = E_DIM;
    const int t = threadIdx.x;
    const int w = t >> 6, lane = t & 63;
    const int quad = lane >> 4, lm = lane & 15;
    const int wy = w >> 1, wx = w & 1;
    const int m0 = blockIdx.x * 128, n0 = blockIdx.y * 128;
    const int lrow  = lane >> 2;
    const int lcol8 = (lane & 3) * 8;

    f32x4 acc[4][4] = {};

    for (int kb = 0; kb < K; kb += 32) {
        __syncthreads();
#pragma unroll
        for (int i = 0; i < 2; ++i) {
            const int r0 = w * 32 + i * 16;
            load_lds16(A + (size_t)(m0 + r0 + lrow) * K + kb + lcol8, &Al[r0 * 32]);
            load_lds16(B + (size_t)(n0 + r0 + lrow) * K + kb + lcol8, &Bl[r0 * 32]);
        }
        __syncthreads();

        bf16x8 af[4], bfr[4];
#pragma unroll
        for (int i = 0; i < 4; ++i)
            af[i] = *(const bf16x8*)(Al + (wy * 64 + i * 16 + lm) * 32 + quad * 8);
#pragma unroll
        for (int j = 0; j < 4; ++j)
            bfr[j] = *(const bf16x8*)(Bl + (wx * 64 + j * 16 + lm) * 32 + quad * 8);
#pragma unroll
        for (int i = 0; i < 4; ++i)
#pragma unroll
            for (int j = 0; j < 4; ++j)
                acc[i][j] = __builtin_amdgcn_mfma_f32_16x16x32_bf16(af[i], bfr[j], acc[i][j], 0, 0, 0);
    }

#pragma unroll
    for (int j = 0; j < 4; ++j) {
        const int n = n0 + wx * 64 + j * 16 + lm;
        const float bs = bias[n];
#pragma unroll
        for (int i = 0; i < 4; ++i) {
            const int mrow = m0 + wy * 64 + i * 16 + quad * 4;
#pragma unroll
            for (int rg = 0; rg < 4; ++rg)
                C[(size_t)(mrow + rg) * N + n] = acc[i][j][rg] + bs;
        }
    }
}

// ---------------------------------------------------------------------------
// attn_v16: 3-stage software pipeline.  R12 lesson: occupancy is NOT the
// lever (4 waves/SIMD in one barrier domain = slower); the cost is the
// serialized phase chain.  Fuse independent stages of 3 consecutive chunks
// into ONE phase with ONE barrier:
//     { V(c-2) | QK^T(c)->S4h[c&1] | softmax(c-1): S4h[~]->P5[~] | PV(c-2) }
//     -> lgkm drain -> s_barrier
// K-load latency hides under softmax VALU; LDS-read latency hides under
// MFMA; exp chain hides under PV.  Double-buffered S4h (2x18.4KB) and P5
// (2x20KB) = 152 KB LDS.  v12 geometry: 512 thr / 8 waves, 2 heads/wave,
// 32 q/block, 32-k chunks, KSPLIT=2, combo->XCD-pair pinning, grid 256.
// Hazard walk: every buffer's writer and reader are in different phases
// separated by drain+barrier; within a phase all buffers touched disjoint.
// v13's S4h rotate-by-quad (free writes) + paired P5 u32 + tree max/sum.
// Buffer choice is LDS POINTER arithmetic (runtime c&1 on addresses is
// safe; register arrays stay statically indexed — R4/R6 spill lesson).
// ---------------------------------------------------------------------------
#define QKT_ST(S4W, KOFF)                                                     \
  _Pragma("unroll")                                                           \
  for (int kt = 0; kt < 2; ++kt) {                                            \
    f32x4 sacc_[2][2];                                                        \
    _Pragma("unroll")                                                         \
    for (int hp = 0; hp < 2; ++hp) {                                          \
      bf16x8 kf0_ = *(const bf16x8*)(K + kmat                                 \
                    + (size_t)((KOFF) + kt * 16 + lm) * E_DIM                 \
                    + (h0 + hp) * 64 + quad * 8);                             \
      bf16x8 kf1_ = *(const bf16x8*)(K + kmat                                 \
                    + (size_t)((KOFF) + kt * 16 + lm) * E_DIM                 \
                    + (h0 + hp) * 64 + 32 + quad * 8);                        \
      _Pragma("unroll")                                                       \
      for (int s = 0; s < 2; ++s) {                                           \
        f32x4 sf_ = {};                                                       \
        sf_ = __builtin_amdgcn_mfma_f32_16x16x32_bf16(kf0_, qf[s][hp][0], sf_, 0, 0, 0); \
        sf_ = __builtin_amdgcn_mfma_f32_16x16x32_bf16(kf1_, qf[s][hp][1], sf_, 0, 0, 0); \
        sacc_[hp][s] = sf_;                                                   \
      }                                                                       \
    }                                                                         \
    _Pragma("unroll")                                                         \
    for (int s = 0; s < 2; ++s)                                               \
      _Pragma("unroll")                                                       \
      for (int rg = 0; rg < 4; ++rg) {                                        \
        union { h16x2 v; unsigned u; } pk_;                                   \
        pk_.v = __builtin_amdgcn_cvt_pkrtz(sacc_[0][s][rg], sacc_[1][s][rg]); \
        const int kl_  = kt * 16 + quad * 4 + rg;                             \
        const int qph_ = ((s * 16 + lm) + 8 * quad) & 31;                     \
        *(unsigned*)((S4W) + (size_t)(kl_ * 32 + qph_) * 18 + 2 * w) = pk_.u; \
      }                                                                       \
  }

#define SM_ST(S4R, P5W)                                                       \
  {                                                                           \
    float pv0[16], pv1[16];                                                   \
    _Pragma("unroll")                                                         \
    for (int e = 0; e < 2; ++e) {                                             \
      const int kk_ = 2 * sj + e;                                             \
      const u16* base_ = (S4R) + (size_t)(kk_ * 32 + qrot) * 18;              \
      union { uint4 u; __fp16 hh[8]; } r0_, r1_;                              \
      r0_.u = *(const uint4*)(base_);                                         \
      r1_.u = *(const uint4*)(base_ + 8);                                     \
      float s_[16];                                                           \
      _Pragma("unroll")                                                       \
      for (int z = 0; z < 8; ++z) {                                           \
        s_[z] = (float)r0_.hh[z]; s_[8 + z] = (float)r1_.hh[z];               \
      }                                                                       \
      const float m_ =                                                        \
          fmaxf(fmaxf(fmaxf(fmaxf(s_[0], s_[1]), fmaxf(s_[2], s_[3])),        \
                      fmaxf(fmaxf(s_[4], s_[5]), fmaxf(s_[6], s_[7]))),       \
                fmaxf(fmaxf(fmaxf(s_[8], s_[9]), fmaxf(s_[10], s_[11])),      \
                      fmaxf(fmaxf(s_[12], s_[13]), fmaxf(s_[14], s_[15])))); \
      _Pragma("unroll")                                                       \
      for (int hh = 0; hh < 16; ++hh)                                         \
        s_[hh] = __builtin_amdgcn_exp2f(s_[hh] - m_);                         \
      const float sum_ =                                                      \
          (((s_[0] + s_[1]) + (s_[2] + s_[3])) + ((s_[4] + s_[5]) + (s_[6] + s_[7]))) + \
          (((s_[8] + s_[9]) + (s_[10] + s_[11])) + ((s_[12] + s_[13]) + (s_[14] + s_[15]))); \
      const float inv_ = __builtin_amdgcn_rcpf(sum_);                         \
      if (e == 0) {                                                           \
        _Pragma("unroll")                                                     \
        for (int hh = 0; hh < 16; ++hh) pv0[hh] = s_[hh] * inv_;              \
      } else {                                                                \
        _Pragma("unroll")                                                     \
        for (int hh = 0; hh < 16; ++hh) pv1[hh] = s_[hh] * inv_;              \
      }                                                                       \
    }                                                                         \
    _Pragma("unroll")                                                         \
    for (int hh = 0; hh < 16; ++hh) {                                         \
      union { h16x2 v; unsigned u; } cv_;                                     \
      cv_.v = __builtin_amdgcn_cvt_pkrtz(pv0[hh], pv1[hh]);                   \
      *(unsigned*)((P5W) + (size_t)hh * 1280 + sq * 40 + 2 * sj) = cv_.u;     \
    }                                                                         \
  }

#define V_ST(KOFF)                                                            \
  _Pragma("unroll")                                                           \
  for (int hp = 0; hp < 2; ++hp)                                              \
    _Pragma("unroll")                                                         \
    for (int dt = 0; dt < 4; ++dt)                                            \
      vf[hp][dt] = *(const f16x8*)(Vt + vtb                                   \
                   + (size_t)((h0 + hp) * 64 + dt * 16 + lm) * S_LEN          \
                   + (KOFF) + quad * 8);

#define PV_ST(P5R)                                                            \
  _Pragma("unroll")                                                           \
  for (int hp = 0; hp < 2; ++hp)                                              \
    _Pragma("unroll")                                                         \
    for (int s = 0; s < 2; ++s) {                                             \
      f16x8 pa_ = *(const f16x8*)((P5R) + (size_t)(h0 + hp) * 1280            \
                                  + (s * 16 + lm) * 40 + quad * 8);           \
      _Pragma("unroll")                                                       \
      for (int dt = 0; dt < 4; ++dt)                                          \
        oacc[hp][s][dt] = __builtin_amdgcn_mfma_f32_16x16x32_f16(             \
                              pa_, vf[hp][dt], oacc[hp][s][dt], 0, 0, 0);     \
    }

#define PHASE_END                                                             \
  asm volatile("s_waitcnt lgkmcnt(0)" ::: "memory");                          \
  __builtin_amdgcn_s_barrier();

__global__ __launch_bounds__(512, 2)
void attn_v16(const u16* __restrict__ Q, const u16* __restrict__ K,
              const u16* __restrict__ Vt, u16* __restrict__ ctxA,
              u16* __restrict__ ctxB)
{
    // S4h[2]: [32 kl][32 qph][18] u16 @ 0 and 18432
    // P5 [2]: [16 h][32 q][40]    u16 @ 36864 and 57344       total 152 KB
    __shared__ __align__(16) u16 smem[77824];

    const int t     = threadIdx.x;   // 0..511
    const int w     = t >> 6;        // 0..7
    const int lane  = t & 63;
    const int quad  = lane >> 4, lm = lane & 15;

    // combo -> XCD-pair pinning (model: XCD = blockIdx % 8).
    const int i     = blockIdx.x;        // 0..255
    const int xcd   = i & 7;
    const int combo = xcd >> 1;          // 0..3
    const int b     = combo >> 1;
    const int khalf = combo & 1;
    const int slot  = i >> 3;            // 0..31
    const int qt    = ((xcd & 1) << 5) | slot;   // 0..63
    const int q0    = qt * 32;

    const size_t qbase = ((size_t)b * S_LEN + q0) * E_DIM;
    const size_t kmat  = (size_t)b * S_LEN * E_DIM;
    const size_t vtb   = (size_t)b * E_DIM * S_LEN;

    const int h0 = 2 * w;                // this wave's first head

    // Q fragments: [subtile][head-pair][hf], loop-invariant (32 regs)
    bf16x8 qf[2][2][2];
#pragma unroll
    for (int s = 0; s < 2; ++s)
#pragma unroll
        for (int hp = 0; hp < 2; ++hp)
#pragma unroll
            for (int hf = 0; hf < 2; ++hf)
                qf[s][hp][hf] = *(const bf16x8*)(Q + qbase
                                + (size_t)(s * 16 + lm) * E_DIM
                                + (h0 + hp) * 64 + hf * 32 + quad * 8);

    f32x4 oacc[2][2][4] = {};   // [hp][subtile][dtile] = 64 acc regs
    f16x8 vf[2][4];             // V regs, re-filled each phase
    const int kbeg = khalf * (S_LEN / 2);
    const int sq = t & 31, sj = t >> 5;  // softmax: q=sq, k in {2sj, 2sj+1}
    // writer quad for k in {2sj,2sj+1} is ((2sj)>>2)&3 = (sj>>1)&3, shared:
    const int qrot = (sq + 8 * ((sj >> 1) & 3)) & 31;

    u16* const S4_0 = smem;
    u16* const S4_1 = smem + 18432;
    u16* const P5_0 = smem + 36864;
    u16* const P5_1 = smem + 57344;

    // ---- pipeline prologue ----
    QKT_ST(S4_0, kbeg)                       // chunk 0 -> S4h[0]
    PHASE_END
    QKT_ST(S4_1, kbeg + 32)                  // chunk 1 -> S4h[1]
    SM_ST (S4_0, P5_0)                       // softmax 0 -> P5[0]
    PHASE_END

    // ---- steady state: c = 2..31: QK^T(c) | SM(c-1) | PV(c-2) ----
    for (int c = 2; c < 32; ++c) {
        u16* S4w = (c & 1) ? S4_1 : S4_0;
        u16* S4r = (c & 1) ? S4_0 : S4_1;
        u16* P5w = (c & 1) ? P5_0 : P5_1;
        u16* P5r = (c & 1) ? P5_1 : P5_0;
        V_ST  (kbeg + (c - 2) * 32)
        QKT_ST(S4w, kbeg + c * 32)
        SM_ST (S4r, P5w)
        PV_ST (P5r)
        PHASE_END
    }

    // ---- pipeline drain: SM(31)|PV(30), then PV(31) ----
    V_ST  (kbeg + 30 * 32)
    SM_ST (S4_1, P5_1)                       // chunk 31 (31&1=1)
    PV_ST (P5_0)                             // chunk 30 (30&1=0)
    PHASE_END
    V_ST  (kbeg + 31 * 32)
    PV_ST (P5_1)                             // chunk 31

    __syncthreads();
    u16* Ol = smem;          // [32 q][1024 e] = 32768 u16 <= 77824 u16
#pragma unroll
    for (int hp = 0; hp < 2; ++hp) {
        const int h = h0 + hp;
#pragma unroll
        for (int s = 0; s < 2; ++s)
#pragma unroll
            for (int dt = 0; dt < 4; ++dt)
#pragma unroll
                for (int rg = 0; rg < 4; ++rg)
                    Ol[(size_t)(s * 16 + quad * 4 + rg) * 1024 + h * 64 + dt * 16 + lm]
                        = f2bf(oacc[hp][s][dt][rg]);
    }
    __syncthreads();
    u16* dst = khalf ? ctxB : ctxA;
#pragma unroll
    for (int i2 = 0; i2 < 8; ++i2) {
        const int unit = i2 * 512 + t;
        const int r = unit >> 7, cu = unit & 127;   // r 0..31
        *(bf16x8*)(dst + ((size_t)b * S_LEN + q0 + r) * E_DIM + cu * 8) =
            *(const bf16x8*)(Ol + (size_t)r * 1024 + cu * 8);
    }
}

#undef QKT_ST
#undef SM_ST
#undef V_ST
#undef PV_ST
#undef PHASE_END

// ---------------------------------------------------------------------------
extern "C" void kernel_launch(void* const* d_in, const int* in_sizes, int n_in,
                              void* d_out, int out_size, void* d_ws, size_t ws_size,
                              hipStream_t stream)
{
    const float* x  = (const float*)d_in[0];
    const float* Wq = (const float*)d_in[1];
    const float* bq = (const float*)d_in[2];
    const float* Wk = (const float*)d_in[3];
    const float* bk = (const float*)d_in[4];
    const float* Wv = (const float*)d_in[5];
    const float* bv = (const float*)d_in[6];
    const float* Wo = (const float*)d_in[7];
    const float* bo = (const float*)d_in[8];
    float* out = (float*)d_out;

    // bf16/fp16 workspace (u16 elems), 56 MB:
    const size_t MAT = (size_t)M_ROWS * E_DIM;   // 4M elems
    const size_t WSZ = (size_t)E_DIM * E_DIM;    // 1M elems
    u16* xb   = (u16*)d_ws;          // x; later combined ctx
    u16* W3   = xb   + MAT;          // Wq|Wk|Wv concat [3072][1024]
    u16* Wob  = W3   + 3 * WSZ;
    u16* Qb   = Wob  + WSZ;
    u16* Kb   = Qb   + MAT;
    u16* Vtb  = Kb   + MAT;          // V transposed [b][e][s], FP16
    u16* ctxA = Vtb  + MAT;
    u16* ctxB = ctxA + MAT;

    // 1) convert inputs to bf16 (QKV weights in one merged launch)
    cvt_bf16<<<(int)(MAT / 1024), 256, 0, stream>>>(x, xb, (int)MAT);
    dim3 wgrid(WSZ / 1024, 3);
    cvt_w3<<<wgrid, 256, 0, stream>>>(Wq, Wk, Wv, W3);
    cvt_bf16<<<(int)(WSZ / 1024), 256, 0, stream>>>(Wo, Wob, (int)WSZ);

    // 2) fused QKV projection (Q pre-scaled, V fp16-transposed)
    dim3 qkvgrid(M_ROWS / 128, 3 * E_DIM / 128);   // 32 x 24 = 768 blocks
    gemm_qkv<<<qkvgrid, 256, 0, stream>>>(xb, W3, bq, bk, bv, Qb, Kb, Vtb);

    // 3) fused MFMA attention: 3-stage pipelined, 32 q/block, 512 thr,
    //    KSPLIT=2, XCD-pinned, grid 256 = 1 block/CU
    attn_v16<<<BATCH * 64 * 2, 512, 0, stream>>>(Qb, Kb, Vtb, ctxA, ctxB);

    // 4) combine k-halves into xb (x is dead)
    combine_ctx<<<(int)(MAT / 1024), 256, 0, stream>>>(ctxA, ctxB, xb, (int)MAT);

    // 5) output projection (fp32 out)
    dim3 ogrid(M_ROWS / 128, E_DIM / 128);         // 32 x 8
    gemm_wo<<<ogrid, 256, 0, stream>>>(xb, Wob, bo, out);
}